// Round 4
// baseline (2590.809 us; speedup 1.0000x reference)
//
#include <hip/hip_runtime.h>

#define BB 128
#define TT 2048
#define DD 64
#define HH 128
#define OO 32

typedef _Float16 f16x8 __attribute__((ext_vector_type(8)));
typedef float    f32x4 __attribute__((ext_vector_type(4)));

#define MFMA16(a,b,c) __builtin_amdgcn_mfma_f32_16x16x32_f16((a),(b),(c),0,0,0)

__device__ __forceinline__ f32x4 load4(const float* p){ return *(const f32x4*)p; }

// A-fragment for 16x16x32: lane(n=lane&15,q=lane>>4) holds A[m=n][k=q*8+j].
__device__ __forceinline__ f16x8 afrag(const float* p){
    float4 a = *(const float4*)p, b = *(const float4*)(p+4);
    f16x8 r;
    r[0]=(_Float16)a.x; r[1]=(_Float16)a.y; r[2]=(_Float16)a.z; r[3]=(_Float16)a.w;
    r[4]=(_Float16)b.x; r[5]=(_Float16)b.y; r[6]=(_Float16)b.z; r[7]=(_Float16)b.w;
    return r;
}

// tanh(u) = 1 - 2*rcp(1 + exp2(u*2/ln2)); 5 VALU ops, saturates at +/-1.
__device__ __forceinline__ float tanh5(float u){
#if __has_builtin(__builtin_amdgcn_exp2f)
    float e = __builtin_amdgcn_exp2f(u * 2.885390081777927f);
#else
    float e = exp2f(u * 2.885390081777927f);
#endif
    return __builtin_fmaf(-2.f, __builtin_amdgcn_rcpf(1.f + e), 1.f);
}

// ---------------------------------------------------------------------------
// proj: xp0[bt][i] = W_ih0[i,:].x[bt,:] + b_ih0[i] + b_hh0[i], fp16 out.
// ---------------------------------------------------------------------------
#define XSTR 72
extern "C" __global__ void __launch_bounds__(256)
proj_kernel(const float* __restrict__ x, const float* __restrict__ W_ih0,
            const float* __restrict__ b_ih0, const float* __restrict__ b_hh0,
            _Float16* __restrict__ xp0)
{
    const int tid = threadIdx.x;
    const int w = tid >> 6, lane = tid & 63;
    const int n = lane & 15, q = lane >> 4;
    const size_t row0 = (size_t)blockIdx.x * 64;

    __shared__ __align__(16) _Float16 XT[64][XSTR];

    #pragma unroll
    for (int it = 0; it < 4; ++it){
        float4 v = *(const float4*)(x + row0*DD + it*1024 + tid*4);
        int rr = it*16 + (tid >> 4), d0 = (tid & 15)*4;
        union { uint2 u; _Float16 h[4]; } c;
        c.h[0]=(_Float16)v.x; c.h[1]=(_Float16)v.y; c.h[2]=(_Float16)v.z; c.h[3]=(_Float16)v.w;
        *(uint2*)&XT[rr][d0] = c.u;
    }

    f16x8 A[8][2]; f32x4 bv[8];
    #pragma unroll
    for (int mt = 0; mt < 8; ++mt){
        #pragma unroll
        for (int kt = 0; kt < 2; ++kt)
            A[mt][kt] = afrag(W_ih0 + (mt*16 + n)*DD + kt*32 + q*8);
        bv[mt] = load4(b_ih0 + mt*16 + q*4) + load4(b_hh0 + mt*16 + q*4);
    }
    __syncthreads();

    const _Float16* xr = &XT[w*16 + n][0];
    f16x8 B0 = *(const f16x8*)(xr + q*8);
    f16x8 B1 = *(const f16x8*)(xr + 32 + q*8);

    _Float16* orow = xp0 + (row0 + w*16 + n)*HH + q*4;
    #pragma unroll
    for (int mt = 0; mt < 8; ++mt){
        f32x4 acc = bv[mt];
        acc = MFMA16(A[mt][0], B0, acc);
        acc = MFMA16(A[mt][1], B1, acc);
        union { uint2 u; _Float16 h[4]; } s;
        #pragma unroll
        for (int r = 0; r < 4; ++r) s.h[r] = (_Float16)acc[r];
        *(uint2*)(orow + mt*16) = s.u;
    }
}

// ---------------------------------------------------------------------------
// fill: out[b][t][:] = b_fc for t >= lengths[b].
// ---------------------------------------------------------------------------
extern "C" __global__ void __launch_bounds__(256)
fill_kernel(const int* __restrict__ lengths, const float* __restrict__ b_fc,
            float* __restrict__ out)
{
    size_t idx = (size_t)blockIdx.x*256 + threadIdx.x;
    #pragma unroll
    for (int k = 0; k < 4; ++k, idx += (size_t)2048*256){
        int o4 = (int)(idx & 7);
        int t  = (int)((idx >> 3) & 2047);
        int b  = (int)(idx >> 14);
        if (t >= lengths[b])
            ((float4*)out)[idx] = *(const float4*)(b_fc + o4*4);
    }
}

// ---------------------------------------------------------------------------
// scan: 8 blocks x 256 thr (4 waves). Block = 16 batch rows (sorted lengths).
// Explicit 4x unroll; xp prefetch ring of 4 NAMED register slots, each written
// only by its own global load (issued at t, consumed at t+4) -> no register
// moves of in-flight loads -> no per-step vmcnt(0) drain (the round-3 stall).
// ---------------------------------------------------------------------------
#define NB   16
#define LSTR 136   // halves; 272B rows, 16B-aligned fragments

#define STEP(T_, P_, XA_, XB_) do {                                           \
    const int t_ = (T_);                                                      \
    f16x8 bh1[4], bh2[4];                                                     \
    _Pragma("unroll")                                                         \
    for (int kt = 0; kt < 4; ++kt){                                           \
        bh1[kt] = *(const f16x8*)&H1T[P_][n][kt*32 + q*8];                    \
        bh2[kt] = *(const f16x8*)&H2T[P_][n][kt*32 + q*8];                    \
    }                                                                         \
    f32x4 z0[2];                                                              \
    const bool doZ0 = (t_ < maxlen);                                          \
    if (doZ0){                                                                \
        union { uint2 u; _Float16 h[4]; } cA, cB; cA.u = XA_; cB.u = XB_;     \
        _Pragma("unroll")                                                     \
        for (int r = 0; r < 4; ++r){ z0[0][r] = (float)cA.h[r];               \
                                     z0[1][r] = (float)cB.h[r]; }             \
        if (t_ + 4 < maxlen){                                                 \
            XA_ = *(const uint2*)(xpbase + (size_t)(t_+4)*HH);                \
            XB_ = *(const uint2*)(xpbase + (size_t)(t_+4)*HH + 16);           \
        }                                                                     \
        _Pragma("unroll")                                                     \
        for (int kt = 0; kt < 4; ++kt){                                       \
            z0[0] = MFMA16(A0[0][kt], bh1[kt], z0[0]);                        \
            z0[1] = MFMA16(A0[1][kt], bh1[kt], z0[1]);                        \
        }                                                                     \
    }                                                                         \
    f32x4 z1[2];                                                              \
    const bool doZ1 = (t_ >= 1) && (t_ <= maxlen);                            \
    if (doZ1){                                                                \
        f32x4 y0, y1;                                                         \
        z1[0] = b1v[0]; z1[1] = b1v[1];                                       \
        y0[0]=0.f;y0[1]=0.f;y0[2]=0.f;y0[3]=0.f; y1=y0;                       \
        _Pragma("unroll")                                                     \
        for (int kt = 0; kt < 4; ++kt){                                       \
            z1[0] = MFMA16(Ai[0][kt], bh1[kt], z1[0]);                        \
            z1[1] = MFMA16(Ai[1][kt], bh1[kt], z1[1]);                        \
            y0    = MFMA16(Ah[0][kt], bh2[kt], y0);                           \
            y1    = MFMA16(Ah[1][kt], bh2[kt], y1);                           \
        }                                                                     \
        z1[0] += y0; z1[1] += y1;                                             \
    }                                                                         \
    if (w >= 2 && t_ >= 2){                                                   \
        f32x4 zf = bfv;                                                       \
        _Pragma("unroll")                                                     \
        for (int kt = 0; kt < 4; ++kt) zf = MFMA16(Af[kt], bh2[kt], zf);      \
        if (t_ - 2 < lenn){                                                   \
            float4 sv; sv.x=zf[0]; sv.y=zf[1]; sv.z=zf[2]; sv.w=zf[3];        \
            *(float4*)(obase + (size_t)(t_-2)*OO) = sv;                       \
        }                                                                     \
    }                                                                         \
    if (doZ0){                                                                \
        _Pragma("unroll")                                                     \
        for (int m = 0; m < 2; ++m){                                          \
            union { uint2 u; _Float16 h[4]; } s;                              \
            _Pragma("unroll")                                                 \
            for (int r = 0; r < 4; ++r) s.h[r] = (_Float16)tanh5(z0[m][r]);   \
            *(uint2*)&H1T[(P_)^1][n][(2*w+m)*16 + q*4] = s.u;                 \
        }                                                                     \
    }                                                                         \
    if (doZ1){                                                                \
        _Pragma("unroll")                                                     \
        for (int m = 0; m < 2; ++m){                                          \
            union { uint2 u; _Float16 h[4]; } s;                              \
            _Pragma("unroll")                                                 \
            for (int r = 0; r < 4; ++r) s.h[r] = (_Float16)tanh5(z1[m][r]);   \
            *(uint2*)&H2T[(P_)^1][n][(2*w+m)*16 + q*4] = s.u;                 \
        }                                                                     \
    }                                                                         \
    asm volatile("s_waitcnt lgkmcnt(0)\n\ts_barrier" ::: "memory");           \
} while (0)

extern "C" __global__ void __launch_bounds__(256, 1)
scan_kernel(const _Float16* __restrict__ xp0, const int* __restrict__ lengths,
            const float* __restrict__ W_hh0,
            const float* __restrict__ W_ih1, const float* __restrict__ W_hh1,
            const float* __restrict__ b_ih1, const float* __restrict__ b_hh1,
            const float* __restrict__ W_fc,  const float* __restrict__ b_fc,
            float* __restrict__ out)
{
    const int tid  = threadIdx.x;
    const int w    = tid >> 6, lane = tid & 63;
    const int n    = lane & 15, q = lane >> 4;
    const int rbase= blockIdx.x * NB;

    __shared__ __align__(16) _Float16 H1T[2][NB][LSTR];
    __shared__ __align__(16) _Float16 H2T[2][NB][LSTR];

    for (int idx = tid; idx < 2*NB*LSTR/2; idx += 256){
        ((unsigned*)H1T)[idx] = 0u;
        ((unsigned*)H2T)[idx] = 0u;
    }

    // ---- stationary weights as A-fragments ----
    f16x8 A0[2][4], Ai[2][4], Ah[2][4];
    #pragma unroll
    for (int m = 0; m < 2; ++m){
        const int row = (2*w + m)*16 + n;
        #pragma unroll
        for (int kt = 0; kt < 4; ++kt){
            A0[m][kt] = afrag(W_hh0 + row*HH + kt*32 + q*8);
            Ai[m][kt] = afrag(W_ih1 + row*HH + kt*32 + q*8);
            Ah[m][kt] = afrag(W_hh1 + row*HH + kt*32 + q*8);
        }
    }
    const int f = w & 1;
    f16x8 Af[4];
    #pragma unroll
    for (int kt = 0; kt < 4; ++kt)
        Af[kt] = afrag(W_fc + (f*16 + n)*HH + kt*32 + q*8);

    f32x4 b1v[2];
    #pragma unroll
    for (int m = 0; m < 2; ++m)
        b1v[m] = load4(b_ih1 + (2*w+m)*16 + q*4) + load4(b_hh1 + (2*w+m)*16 + q*4);
    const f32x4 bfv = load4(b_fc + f*16 + q*4);

    const int lenn = lengths[rbase + n];
    int mx = lenn;
    #pragma unroll
    for (int s = 1; s < 16; s <<= 1){ int o = __shfl_xor(mx, s, 64); mx = max(mx, o); }
    const int maxlen = __builtin_amdgcn_readfirstlane(mx);

    const _Float16* xpbase = xp0 + ((size_t)(rbase+n)*TT)*HH + (2*w)*16 + q*4;
    float* obase = out + ((size_t)(rbase+n)*TT)*OO + f*16 + q*4;

    // ---- prefetch ring: 4 named slots, depth 4 ----
    uint2 xrA0={0,0}, xrB0={0,0}, xrA1={0,0}, xrB1={0,0};
    uint2 xrA2={0,0}, xrB2={0,0}, xrA3={0,0}, xrB3={0,0};
    xrA0 = *(const uint2*)(xpbase);
    xrB0 = *(const uint2*)(xpbase + 16);
    if (1 < maxlen){ xrA1 = *(const uint2*)(xpbase + (size_t)1*HH);
                     xrB1 = *(const uint2*)(xpbase + (size_t)1*HH + 16); }
    if (2 < maxlen){ xrA2 = *(const uint2*)(xpbase + (size_t)2*HH);
                     xrB2 = *(const uint2*)(xpbase + (size_t)2*HH + 16); }
    if (3 < maxlen){ xrA3 = *(const uint2*)(xpbase + (size_t)3*HH);
                     xrB3 = *(const uint2*)(xpbase + (size_t)3*HH + 16); }

    __syncthreads();

    for (int t0 = 0; t0 <= maxlen + 1; t0 += 4){
        STEP(t0+0, 0, xrA0, xrB0);
        STEP(t0+1, 1, xrA1, xrB1);
        STEP(t0+2, 0, xrA2, xrB2);
        STEP(t0+3, 1, xrA3, xrB3);
    }
}

// ---------------------------------------------------------------------------
extern "C" void kernel_launch(void* const* d_in, const int* in_sizes, int n_in,
                              void* d_out, int out_size, void* d_ws, size_t ws_size,
                              hipStream_t stream)
{
    const float* x       = (const float*)d_in[0];
    const int*   lengths = (const int*)  d_in[1];
    const float* W_ih0   = (const float*)d_in[2];
    const float* W_hh0   = (const float*)d_in[3];
    const float* b_ih0   = (const float*)d_in[4];
    const float* b_hh0   = (const float*)d_in[5];
    const float* W_ih1   = (const float*)d_in[6];
    const float* W_hh1   = (const float*)d_in[7];
    const float* b_ih1   = (const float*)d_in[8];
    const float* b_hh1   = (const float*)d_in[9];
    const float* W_fc    = (const float*)d_in[10];
    const float* b_fc    = (const float*)d_in[11];

    _Float16* xp = (_Float16*)d_ws;   // [B*T][128] fp16 = 64 MiB

    proj_kernel<<<BB*TT/64, 256, 0, stream>>>(x, W_ih0, b_ih0, b_hh0, xp);
    fill_kernel<<<2048, 256, 0, stream>>>(lengths, b_fc, (float*)d_out);
    scan_kernel<<<BB/NB, 256, 0, stream>>>(xp, lengths, W_hh0,
                                           W_ih1, W_hh1, b_ih1, b_hh1,
                                           W_fc, b_fc, (float*)d_out);
}

// Round 5
// 2059.437 us; speedup vs baseline: 1.2580x; 1.2580x over previous
//
#include <hip/hip_runtime.h>

#define BB 128
#define TT 2048
#define DD 64
#define HH 128
#define OO 32

typedef _Float16 f16x8 __attribute__((ext_vector_type(8)));
typedef float    f32x4 __attribute__((ext_vector_type(4)));

#define MFMA16(a,b,c) __builtin_amdgcn_mfma_f32_16x16x32_f16((a),(b),(c),0,0,0)

__device__ __forceinline__ f32x4 load4(const float* p){ return *(const f32x4*)p; }

// A-fragment for 16x16x32: lane(n=lane&15,q=lane>>4) holds A[m=n][k=q*8+j].
__device__ __forceinline__ f16x8 afrag(const float* p){
    float4 a = *(const float4*)p, b = *(const float4*)(p+4);
    f16x8 r;
    r[0]=(_Float16)a.x; r[1]=(_Float16)a.y; r[2]=(_Float16)a.z; r[3]=(_Float16)a.w;
    r[4]=(_Float16)b.x; r[5]=(_Float16)b.y; r[6]=(_Float16)b.z; r[7]=(_Float16)b.w;
    return r;
}

// tanh(u) = 1 - 2*rcp(1 + exp2(u*2/ln2)); 5 VALU ops, saturates at +/-1.
__device__ __forceinline__ float tanh5(float u){
#if __has_builtin(__builtin_amdgcn_exp2f)
    float e = __builtin_amdgcn_exp2f(u * 2.885390081777927f);
#else
    float e = exp2f(u * 2.885390081777927f);
#endif
    return __builtin_fmaf(-2.f, __builtin_amdgcn_rcpf(1.f + e), 1.f);
}

// ---------------------------------------------------------------------------
// proj: xp0[bt][i] = W_ih0[i,:].x[bt,:] + b_ih0[i] + b_hh0[i], fp16 out.
// ---------------------------------------------------------------------------
#define XSTR 72
extern "C" __global__ void __launch_bounds__(256)
proj_kernel(const float* __restrict__ x, const float* __restrict__ W_ih0,
            const float* __restrict__ b_ih0, const float* __restrict__ b_hh0,
            _Float16* __restrict__ xp0)
{
    const int tid = threadIdx.x;
    const int w = tid >> 6, lane = tid & 63;
    const int n = lane & 15, q = lane >> 4;
    const size_t row0 = (size_t)blockIdx.x * 64;

    __shared__ __align__(16) _Float16 XT[64][XSTR];

    #pragma unroll
    for (int it = 0; it < 4; ++it){
        float4 v = *(const float4*)(x + row0*DD + it*1024 + tid*4);
        int rr = it*16 + (tid >> 4), d0 = (tid & 15)*4;
        union { uint2 u; _Float16 h[4]; } c;
        c.h[0]=(_Float16)v.x; c.h[1]=(_Float16)v.y; c.h[2]=(_Float16)v.z; c.h[3]=(_Float16)v.w;
        *(uint2*)&XT[rr][d0] = c.u;
    }

    f16x8 A[8][2]; f32x4 bv[8];
    #pragma unroll
    for (int mt = 0; mt < 8; ++mt){
        #pragma unroll
        for (int kt = 0; kt < 2; ++kt)
            A[mt][kt] = afrag(W_ih0 + (mt*16 + n)*DD + kt*32 + q*8);
        bv[mt] = load4(b_ih0 + mt*16 + q*4) + load4(b_hh0 + mt*16 + q*4);
    }
    __syncthreads();

    const _Float16* xr = &XT[w*16 + n][0];
    f16x8 B0 = *(const f16x8*)(xr + q*8);
    f16x8 B1 = *(const f16x8*)(xr + 32 + q*8);

    _Float16* orow = xp0 + (row0 + w*16 + n)*HH + q*4;
    #pragma unroll
    for (int mt = 0; mt < 8; ++mt){
        f32x4 acc = bv[mt];
        acc = MFMA16(A[mt][0], B0, acc);
        acc = MFMA16(A[mt][1], B1, acc);
        union { uint2 u; _Float16 h[4]; } s;
        #pragma unroll
        for (int r = 0; r < 4; ++r) s.h[r] = (_Float16)acc[r];
        *(uint2*)(orow + mt*16) = s.u;
    }
}

// ---------------------------------------------------------------------------
// fill: out[b][t][:] = b_fc for t >= lengths[b].
// ---------------------------------------------------------------------------
extern "C" __global__ void __launch_bounds__(256)
fill_kernel(const int* __restrict__ lengths, const float* __restrict__ b_fc,
            float* __restrict__ out)
{
    size_t idx = (size_t)blockIdx.x*256 + threadIdx.x;
    #pragma unroll
    for (int k = 0; k < 4; ++k, idx += (size_t)2048*256){
        int o4 = (int)(idx & 7);
        int t  = (int)((idx >> 3) & 2047);
        int b  = (int)(idx >> 14);
        if (t >= lengths[b])
            ((float4*)out)[idx] = *(const float4*)(b_fc + o4*4);
    }
}

// ---------------------------------------------------------------------------
// scan: 4 blocks x 512 thr (8 waves). Each block = TWO independent 16-row
// groups (ping-pong): grp g = waves 4g..4g+3, rows blockIdx*32+16g..+16.
// Groups share the CU: when one group's waves stall (LDS latency, MFMA dep,
// sync skew), the other group's waves issue -> latency hiding at 2 waves/SIMD.
// Per-group sync = LDS counter (release add after lgkmcnt(0), acquire poll),
// NOT s_barrier (which would couple the groups). STEP body == round-3.
// ---------------------------------------------------------------------------
#define NB   16
#define LSTR 136   // halves; 272B rows, 16B-aligned fragments

extern "C" __global__ void __launch_bounds__(512, 2)
scan_kernel(const _Float16* __restrict__ xp0, const int* __restrict__ lengths,
            const float* __restrict__ W_hh0,
            const float* __restrict__ W_ih1, const float* __restrict__ W_hh1,
            const float* __restrict__ b_ih1, const float* __restrict__ b_hh1,
            const float* __restrict__ W_fc,  const float* __restrict__ b_fc,
            float* __restrict__ out)
{
    const int tid  = threadIdx.x;
    const int grp  = tid >> 8;            // 0 or 1: independent row-group
    const int wtid = tid & 255;
    const int w    = wtid >> 6, lane = wtid & 63;
    const int n    = lane & 15, q = lane >> 4;
    const int rbase= blockIdx.x * 32 + grp * NB;

    __shared__ __align__(16) _Float16 H1T[2][2][NB][LSTR];   // [parity][grp]
    __shared__ __align__(16) _Float16 H2T[2][2][NB][LSTR];
    __shared__ unsigned ctr[2];

    // zero own group's buffers (both parities)
    for (int idx = wtid; idx < NB*LSTR/2; idx += 256){
        ((unsigned*)&H1T[0][grp][0][0])[idx] = 0u;
        ((unsigned*)&H1T[1][grp][0][0])[idx] = 0u;
        ((unsigned*)&H2T[0][grp][0][0])[idx] = 0u;
        ((unsigned*)&H2T[1][grp][0][0])[idx] = 0u;
    }
    if (tid < 2) ctr[tid] = 0u;

    // ---- stationary weights as A-fragments ----
    f16x8 A0[2][4], Ai[2][4], Ah[2][4];
    #pragma unroll
    for (int m = 0; m < 2; ++m){
        const int row = (2*w + m)*16 + n;
        #pragma unroll
        for (int kt = 0; kt < 4; ++kt){
            A0[m][kt] = afrag(W_hh0 + row*HH + kt*32 + q*8);
            Ai[m][kt] = afrag(W_ih1 + row*HH + kt*32 + q*8);
            Ah[m][kt] = afrag(W_hh1 + row*HH + kt*32 + q*8);
        }
    }
    const int f = w & 1;                  // fc m-tile for waves 2,3
    f16x8 Af[4];
    #pragma unroll
    for (int kt = 0; kt < 4; ++kt)
        Af[kt] = afrag(W_fc + (f*16 + n)*HH + kt*32 + q*8);

    f32x4 b1v[2];
    #pragma unroll
    for (int m = 0; m < 2; ++m)
        b1v[m] = load4(b_ih1 + (2*w+m)*16 + q*4) + load4(b_hh1 + (2*w+m)*16 + q*4);
    const f32x4 bfv = load4(b_fc + f*16 + q*4);

    const int lenn = lengths[rbase + n];
    int mx = lenn;
    #pragma unroll
    for (int s = 1; s < 16; s <<= 1){ int o = __shfl_xor(mx, s, 64); mx = max(mx, o); }
    const int maxlen = __builtin_amdgcn_readfirstlane(mx);

    const _Float16* xpbase = xp0 + ((size_t)(rbase+n)*TT)*HH + (2*w)*16 + q*4;
    float* obase = out + ((size_t)(rbase+n)*TT)*OO + f*16 + q*4;

    // ---- xp0 prefetch (2 steps deep) ----
    uint2 xcA, xcB, xnA, xnB;
    xcA = *(const uint2*)(xpbase);            xcB = *(const uint2*)(xpbase + 16);
    if (1 < maxlen){ xnA = *(const uint2*)(xpbase + HH); xnB = *(const uint2*)(xpbase + HH + 16); }

    __syncthreads();   // the ONLY whole-block barrier; groups independent after

    unsigned tgt = 4u;
    for (int t = 0; t <= maxlen + 1; ++t){
        const int p = t & 1, pn = p ^ 1;

        // B-fragments (shared by Z0, Z1, fc)
        f16x8 bh1[4], bh2[4];
        #pragma unroll
        for (int kt = 0; kt < 4; ++kt){
            bh1[kt] = *(const f16x8*)&H1T[p][grp][n][kt*32 + q*8];
            bh2[kt] = *(const f16x8*)&H2T[p][grp][n][kt*32 + q*8];
        }

        // ---- layer0: Z0 = Whh0 . H1[t-1] + xp0[t] ----
        f32x4 z0[2];
        const bool doZ0 = (t < maxlen);
        if (doZ0){
            {
                union { uint2 u; _Float16 h[4]; } cA, cB; cA.u = xcA; cB.u = xcB;
                #pragma unroll
                for (int r = 0; r < 4; ++r){ z0[0][r] = (float)cA.h[r]; z0[1][r] = (float)cB.h[r]; }
            }
            if (t + 2 < maxlen){
                xcA = *(const uint2*)(xpbase + (size_t)(t+2)*HH);
                xcB = *(const uint2*)(xpbase + (size_t)(t+2)*HH + 16);
            }
            #pragma unroll
            for (int kt = 0; kt < 4; ++kt){
                z0[0] = MFMA16(A0[0][kt], bh1[kt], z0[0]);
                z0[1] = MFMA16(A0[1][kt], bh1[kt], z0[1]);
            }
        }

        // ---- layer1: Z1 = Wih1 . H1[t-1] + Whh1 . H2[t-2] + b1 ----
        f32x4 z1[2];
        const bool doZ1 = (t >= 1) && (t <= maxlen);
        if (doZ1){
            z1[0] = b1v[0]; z1[1] = b1v[1];
            #pragma unroll
            for (int kt = 0; kt < 4; ++kt){
                z1[0] = MFMA16(Ai[0][kt], bh1[kt], z1[0]);
                z1[1] = MFMA16(Ai[1][kt], bh1[kt], z1[1]);
            }
            #pragma unroll
            for (int kt = 0; kt < 4; ++kt){
                z1[0] = MFMA16(Ah[0][kt], bh2[kt], z1[0]);
                z1[1] = MFMA16(Ah[1][kt], bh2[kt], z1[1]);
            }
        }

        // ---- fc: out[t-2] = Wfc . H2[t-2] + b_fc (waves 2,3) ----
        if (w >= 2 && t >= 2){
            f32x4 zf = bfv;
            #pragma unroll
            for (int kt = 0; kt < 4; ++kt) zf = MFMA16(Af[kt], bh2[kt], zf);
            if (t - 2 < lenn){
                float4 sv; sv.x = zf[0]; sv.y = zf[1]; sv.z = zf[2]; sv.w = zf[3];
                *(float4*)(obase + (size_t)(t-2)*OO) = sv;
            }
        }

        // ---- tanh + pack + state writes (into parity pn) ----
        if (doZ0){
            #pragma unroll
            for (int m = 0; m < 2; ++m){
                union { uint2 u; _Float16 h[4]; } s;
                #pragma unroll
                for (int r = 0; r < 4; ++r) s.h[r] = (_Float16)tanh5(z0[m][r]);
                *(uint2*)&H1T[pn][grp][n][(2*w+m)*16 + q*4] = s.u;
            }
        }
        if (doZ1){
            #pragma unroll
            for (int m = 0; m < 2; ++m){
                union { uint2 u; _Float16 h[4]; } s;
                #pragma unroll
                for (int r = 0; r < 4; ++r) s.h[r] = (_Float16)tanh5(z1[m][r]);
                *(uint2*)&H2T[pn][grp][n][(2*w+m)*16 + q*4] = s.u;
            }
        }

        // rotate xp prefetch buffers
        { uint2 tA = xcA; xcA = xnA; xnA = tA; uint2 tB = xcB; xcB = xnB; xnB = tB; }

        // ---- group-local sync (replaces s_barrier; does not couple groups) ----
        asm volatile("s_waitcnt lgkmcnt(0)" ::: "memory");   // my LDS writes done
        if (lane == 0)
            __hip_atomic_fetch_add(&ctr[grp], 1u, __ATOMIC_RELEASE,
                                   __HIP_MEMORY_SCOPE_WORKGROUP);
        while (__hip_atomic_load(&ctr[grp], __ATOMIC_ACQUIRE,
                                 __HIP_MEMORY_SCOPE_WORKGROUP) < tgt)
            __builtin_amdgcn_s_sleep(1);
        tgt += 4u;
    }
}

// ---------------------------------------------------------------------------
extern "C" void kernel_launch(void* const* d_in, const int* in_sizes, int n_in,
                              void* d_out, int out_size, void* d_ws, size_t ws_size,
                              hipStream_t stream)
{
    const float* x       = (const float*)d_in[0];
    const int*   lengths = (const int*)  d_in[1];
    const float* W_ih0   = (const float*)d_in[2];
    const float* W_hh0   = (const float*)d_in[3];
    const float* b_ih0   = (const float*)d_in[4];
    const float* b_hh0   = (const float*)d_in[5];
    const float* W_ih1   = (const float*)d_in[6];
    const float* W_hh1   = (const float*)d_in[7];
    const float* b_ih1   = (const float*)d_in[8];
    const float* b_hh1   = (const float*)d_in[9];
    const float* W_fc    = (const float*)d_in[10];
    const float* b_fc    = (const float*)d_in[11];

    _Float16* xp = (_Float16*)d_ws;   // [B*T][128] fp16 = 64 MiB

    proj_kernel<<<BB*TT/64, 256, 0, stream>>>(x, W_ih0, b_ih0, b_hh0, xp);
    fill_kernel<<<2048, 256, 0, stream>>>(lengths, b_fc, (float*)d_out);
    scan_kernel<<<BB/32, 512, 0, stream>>>(xp, lengths, W_hh0,
                                           W_ih1, W_hh1, b_ih1, b_hh1,
                                           W_fc, b_fc, (float*)d_out);
}